// Round 5
// baseline (112.394 us; speedup 1.0000x reference)
//
#include <hip/hip_runtime.h>
#include <hip/hip_bf16.h>

#define NUM_AGES 100
#define FEAT 512
#define BATCH 4096
#define EPSF 1e-6f
#define INV_T 10.0f
#define INV_NORM (1.0f / ((float)BATCH * (float)(BATCH - 1)))

#define BM 128
#define BN 64
#define BK 32
// kept tiles: bx >= 2*by, by in [0,32), bx in [0,64) -> sum(64-2*by) = 1056
#define NTILES 1056

typedef __bf16 bf16_t;
typedef __bf16 v8bf __attribute__((ext_vector_type(8)));
typedef float v4f __attribute__((ext_vector_type(4)));

// async global->LDS, 16B per lane; LDS dest is wave-uniform base + lane*16
__device__ __forceinline__ void async16(const void* g, void* l) {
  __builtin_amdgcn_global_load_lds(
      (const __attribute__((address_space(1))) void*)g,
      (__attribute__((address_space(3))) void*)l, 16, 0, 0);
}

// ---------------- kernel 0: counting sort by age (+ zero the output) ------
__global__ __launch_bounds__(1024) void sort_kernel(
    const int* __restrict__ ages, int* __restrict__ perm, float* __restrict__ out)
{
  __shared__ int hist[NUM_AGES];
  __shared__ int base[NUM_AGES];
  int t = threadIdx.x;
  if (t == 0) out[0] = 0.0f;              // pair_kernel accumulates into out
  if (t < NUM_AGES) hist[t] = 0;
  __syncthreads();
  for (int j = t; j < BATCH; j += 1024) {
    int a = ages[j];
    a = a < 0 ? 0 : (a > NUM_AGES - 1 ? NUM_AGES - 1 : a);
    atomicAdd(&hist[a], 1);
  }
  __syncthreads();
  if (t == 0) {
    int s = 0;
    for (int a = 0; a < NUM_AGES; ++a) { base[a] = s; s += hist[a]; }
  }
  __syncthreads();
  for (int j = t; j < BATCH; j += 1024) {
    int a = ages[j];
    a = a < 0 ? 0 : (a > NUM_AGES - 1 ? NUM_AGES - 1 : a);
    int pos = atomicAdd(&base[a], 1);
    perm[pos] = j;
  }
}

// ---------------- kernel 1: per-sample prep (sorted order) ----------------
__global__ __launch_bounds__(256) void prep_kernel(
    const float* __restrict__ z, const int* __restrict__ ages,
    const float* __restrict__ proxies, const int* __restrict__ perm,
    bf16_t* __restrict__ zb, bf16_t* __restrict__ wb,
    float* __restrict__ sq, float* __restrict__ hd,
    int* __restrict__ ages_s)
{
  int j = blockIdx.x;          // sorted position
  int s = perm[j];             // original sample index
  int t = threadIdx.x;
  int araw = ages[s];
  int a = araw < 0 ? 0 : (araw > NUM_AGES - 1 ? NUM_AGES - 1 : araw);
  const float* cc = proxies + (size_t)a * FEAT;
  const float* cn = proxies + (size_t)(a + 1 > NUM_AGES - 1 ? NUM_AGES - 1 : a + 1) * FEAT;
  const float* cp = proxies + (size_t)(a - 1 < 0 ? 0 : a - 1) * FEAT;
  const float* zr = z + (size_t)s * FEAT;

  float zf[2], dff[2], dbf[2];
  float s_ff = 0.f, s_bb = 0.f, s_zz = 0.f, s_zf = 0.f, s_zb = 0.f;
#pragma unroll
  for (int e = 0; e < 2; ++e) {
    int c = t + e * 256;
    float ccv = cc[c];
    dff[e] = cn[c] - ccv;
    dbf[e] = cp[c] - ccv;
    zf[e] = zr[c];
    s_ff += dff[e] * dff[e];
    s_bb += dbf[e] * dbf[e];
    s_zz += zf[e] * zf[e];
    s_zf += zf[e] * dff[e];
    s_zb += zf[e] * dbf[e];
  }
#pragma unroll
  for (int off = 32; off > 0; off >>= 1) {
    s_ff += __shfl_down(s_ff, off, 64);
    s_bb += __shfl_down(s_bb, off, 64);
    s_zz += __shfl_down(s_zz, off, 64);
    s_zf += __shfl_down(s_zf, off, 64);
    s_zb += __shfl_down(s_zb, off, 64);
  }
  __shared__ float red[4][5];
  int wv = t >> 6, lane = t & 63;
  if (lane == 0) {
    red[wv][0] = s_ff; red[wv][1] = s_bb; red[wv][2] = s_zz;
    red[wv][3] = s_zf; red[wv][4] = s_zb;
  }
  __syncthreads();
  float ff = red[0][0] + red[1][0] + red[2][0] + red[3][0];
  float bb = red[0][1] + red[1][1] + red[2][1] + red[3][1];
  float zz = red[0][2] + red[1][2] + red[2][2] + red[3][2];
  float zdf = red[0][3] + red[1][3] + red[2][3] + red[3][3];
  float zdb = red[0][4] + red[1][4] + red[2][4] + red[3][4];

  float rf = 1.0f / (sqrtf(ff) + EPSF);
  float rb = 1.0f / (sqrtf(bb) + EPSF);
#pragma unroll
  for (int e = 0; e < 2; ++e) {
    int c = t + e * 256;
    float wval = dbf[e] * rb - dff[e] * rf;
    wb[(size_t)j * FEAT + c] = (bf16_t)wval;
    zb[(size_t)j * FEAT + c] = (bf16_t)zf[e];
  }
  if (t == 0) {
    sq[j] = zz;
    hd[j] = rb * zdb - rf * zdf;
    ages_s[j] = araw;
  }
}

// ---------------- kernel 2: fused pairwise tile (upper-tri band only) ----
// Age-sorted samples; tiles with i_min >= j_max+1 contribute 0 -> skipped.
// 124 total regs/wave (60 arch + 64 AGPR) -> 4 waves/SIMD via bounds(256,4).
__global__ __launch_bounds__(256, 4) void pair_kernel(
    const bf16_t* __restrict__ zb, const bf16_t* __restrict__ wb,
    const float* __restrict__ sq, const float* __restrict__ hd,
    const int* __restrict__ ages, float* __restrict__ out)
{
  // A: 128x32 bf16 = 8192 B | Z: 64x32 = 4096 B | W: 64x32 = 4096 B
  __shared__ __attribute__((aligned(16))) char lds[16384];
  __shared__ float s_sqi[BM];
  __shared__ int   s_agei[BM];
  __shared__ float s_sqj[BN];
  __shared__ float s_hdj[BN];
  __shared__ int   s_agej[BN];
  __shared__ float wsum[4];

  int t = threadIdx.x;
  int wv = t >> 6, lane = t & 63;

  // linear tile id -> (by, bx) with bx >= 2*by; row by has 64-2*by tiles
  int rem = blockIdx.x;
  int by = 0;
  while (rem >= 64 - 2 * by) { rem -= 64 - 2 * by; ++by; }
  int bx = 2 * by + rem;
  int i0 = by * BM, j0 = bx * BN;

  if (t < BM) {
    s_sqi[t] = sq[i0 + t];
    s_agei[t] = ages[i0 + t];
  } else if (t < BM + BN) {
    int u = t - BM;
    s_sqj[u] = sq[j0 + u];
    s_hdj[u] = hd[j0 + u];
    s_agej[u] = ages[j0 + u];
  }

  v4f accG[4][2], accH[4][2];
#pragma unroll
  for (int a = 0; a < 4; ++a)
#pragma unroll
    for (int b = 0; b < 2; ++b) {
      accG[a][b] = (v4f){0.f, 0.f, 0.f, 0.f};
      accH[a][b] = (v4f){0.f, 0.f, 0.f, 0.f};
    }

  int wm = wv >> 1, wn = wv & 1;        // wave grid 2x2: 64 rows x 32 cols each
  int lm = lane & 15, q = lane >> 4;

  int grow = lane >> 2;                 // row within 16-row chunk
  int gcol = (lane & 3) * 8;            // bf16 element offset within 32-wide K slab

  const bf16_t* pA0 = zb + (size_t)(i0 + wv * 16 + grow) * FEAT + gcol;
  const bf16_t* pA1 = zb + (size_t)(i0 + 64 + wv * 16 + grow) * FEAT + gcol;
  const bf16_t* pZ  = zb + (size_t)(j0 + wv * 16 + grow) * FEAT + gcol;
  const bf16_t* pW  = wb + (size_t)(j0 + wv * 16 + grow) * FEAT + gcol;
  char* dA0 = lds + wv * 1024;
  char* dA1 = lds + 4096 + wv * 1024;
  char* dZ  = lds + 8192 + wv * 1024;
  char* dW  = lds + 12288 + wv * 1024;

  for (int k0 = 0; k0 < FEAT; k0 += BK) {
    async16(pA0, dA0);
    async16(pA1, dA1);
    async16(pZ, dZ);
    async16(pW, dW);
    pA0 += BK; pA1 += BK; pZ += BK; pW += BK;
    __syncthreads();

    v8bf afr[4], bz[2], bw[2];
#pragma unroll
    for (int mi = 0; mi < 4; ++mi) {
      int r = wm * 64 + mi * 16 + lm;
      afr[mi] = *(const v8bf*)(lds + r * 64 + q * 16);
    }
#pragma unroll
    for (int ni = 0; ni < 2; ++ni) {
      int r = wn * 32 + ni * 16 + lm;
      bz[ni] = *(const v8bf*)(lds + 8192 + r * 64 + q * 16);
      bw[ni] = *(const v8bf*)(lds + 12288 + r * 64 + q * 16);
    }
#pragma unroll
    for (int mi = 0; mi < 4; ++mi)
#pragma unroll
      for (int ni = 0; ni < 2; ++ni) {
        accG[mi][ni] = __builtin_amdgcn_mfma_f32_16x16x32_bf16(afr[mi], bz[ni], accG[mi][ni], 0, 0, 0);
        accH[mi][ni] = __builtin_amdgcn_mfma_f32_16x16x32_bf16(afr[mi], bw[ni], accH[mi][ni], 0, 0, 0);
      }
    __syncthreads();
  }

  // epilogue: C/D layout col = lane&15 (-> j), row = q*4 + reg (-> i)
  float tsum = 0.f;
#pragma unroll
  for (int ni = 0; ni < 2; ++ni) {
    int jl = wn * 32 + ni * 16 + lm;
    float sqj = s_sqj[jl];
    float hdj = s_hdj[jl];
    int aj = s_agej[jl];
#pragma unroll
    for (int mi = 0; mi < 4; ++mi) {
#pragma unroll
      for (int r = 0; r < 4; ++r) {
        int il = wm * 64 + mi * 16 + q * 4 + r;
        float g = accG[mi][ni][r];
        float h = accH[mi][ni][r];
        float d2 = fmaxf(s_sqi[il] + sqj - 2.0f * g, 1e-12f);
        float rs = __builtin_amdgcn_rsqf(d2);
        float arg = (h - hdj) * INV_T * rs;
        float sp = fmaxf(arg, 0.0f) + __logf(1.0f + __expf(-fabsf(arg)));
        tsum += (s_agei[il] < aj) ? sp : 0.0f;
      }
    }
  }

#pragma unroll
  for (int off = 32; off > 0; off >>= 1) tsum += __shfl_down(tsum, off, 64);
  if (lane == 0) wsum[wv] = tsum;
  __syncthreads();
  if (t == 0)
    atomicAdd(out, (wsum[0] + wsum[1] + wsum[2] + wsum[3]) * INV_NORM);
}

extern "C" void kernel_launch(void* const* d_in, const int* in_sizes, int n_in,
                              void* d_out, int out_size, void* d_ws, size_t ws_size,
                              hipStream_t stream) {
  const float* z = (const float*)d_in[0];
  const int* ages = (const int*)d_in[1];
  const float* proxies = (const float*)d_in[2];
  float* out = (float*)d_out;

  char* ws = (char*)d_ws;
  bf16_t* zb = (bf16_t*)ws;                                   // 4 MB
  bf16_t* wb = (bf16_t*)(ws + (size_t)4 * 1024 * 1024);       // 4 MB
  size_t o = (size_t)8 * 1024 * 1024;
  float* sq      = (float*)(ws + o);            // 16 KB
  float* hd      = (float*)(ws + o + 16384);    // 16 KB
  int*   perm    = (int*)  (ws + o + 32768);    // 16 KB
  int*   ages_s  = (int*)  (ws + o + 49152);    // 16 KB

  sort_kernel<<<1, 1024, 0, stream>>>(ages, perm, out);
  prep_kernel<<<BATCH, 256, 0, stream>>>(z, ages, proxies, perm, zb, wb, sq, hd, ages_s);
  pair_kernel<<<NTILES, 256, 0, stream>>>(zb, wb, sq, hd, ages_s, out);
}

// Round 6
// 111.153 us; speedup vs baseline: 1.0112x; 1.0112x over previous
//
#include <hip/hip_runtime.h>
#include <hip/hip_bf16.h>

#define NUM_AGES 100
#define FEAT 512
#define BATCH 4096
#define EPSF 1e-6f
#define INV_T 10.0f
#define INV_NORM (1.0f / ((float)BATCH * (float)(BATCH - 1)))

#define BM 128
#define BN 64
#define BK 32
// kept tiles: bx >= 2*by, by in [0,32), bx in [0,64) -> sum(64-2*by) = 1056
#define NTILES 1056

typedef __bf16 bf16_t;
typedef __bf16 v8bf __attribute__((ext_vector_type(8)));
typedef float v4f __attribute__((ext_vector_type(4)));

// async global->LDS, 16B per lane; LDS dest is wave-uniform base + lane*16
__device__ __forceinline__ void async16(const void* g, void* l) {
  __builtin_amdgcn_global_load_lds(
      (const __attribute__((address_space(1))) void*)g,
      (__attribute__((address_space(3))) void*)l, 16, 0, 0);
}

// ---------------- kernel 0: counting sort by age (+ zero the output) ------
__global__ __launch_bounds__(1024) void sort_kernel(
    const int* __restrict__ ages, int* __restrict__ perm, float* __restrict__ out)
{
  __shared__ int hist[NUM_AGES];
  __shared__ int base[NUM_AGES];
  int t = threadIdx.x;
  if (t == 0) out[0] = 0.0f;              // pair_kernel accumulates into out
  if (t < NUM_AGES) hist[t] = 0;
  __syncthreads();
  for (int j = t; j < BATCH; j += 1024) {
    int a = ages[j];
    a = a < 0 ? 0 : (a > NUM_AGES - 1 ? NUM_AGES - 1 : a);
    atomicAdd(&hist[a], 1);
  }
  __syncthreads();
  if (t == 0) {
    int s = 0;
    for (int a = 0; a < NUM_AGES; ++a) { base[a] = s; s += hist[a]; }
  }
  __syncthreads();
  for (int j = t; j < BATCH; j += 1024) {
    int a = ages[j];
    a = a < 0 ? 0 : (a > NUM_AGES - 1 ? NUM_AGES - 1 : a);
    int pos = atomicAdd(&base[a], 1);
    perm[pos] = j;
  }
}

// ---------------- kernel 1: per-sample prep (sorted order, pre-swizzled) --
// zb/wb columns are stored XOR-swizzled: within each 64B (32-elem) K-slab,
// the 16B granule q of row j sits at position q ^ ((j>>1)&3). pair_kernel's
// monotonic global_load_lds staging then lands a conflict-free LDS layout
// (2-way, free per m136) with zero change to its global access pattern
// (R2 lesson: permuting the staging lanes' global addresses cost 31%).
__global__ __launch_bounds__(256) void prep_kernel(
    const float* __restrict__ z, const int* __restrict__ ages,
    const float* __restrict__ proxies, const int* __restrict__ perm,
    bf16_t* __restrict__ zb, bf16_t* __restrict__ wb,
    float* __restrict__ sq, float* __restrict__ hd,
    int* __restrict__ ages_s)
{
  int j = blockIdx.x;          // sorted position
  int s = perm[j];             // original sample index
  int t = threadIdx.x;
  int araw = ages[s];
  int a = araw < 0 ? 0 : (araw > NUM_AGES - 1 ? NUM_AGES - 1 : araw);
  const float* cc = proxies + (size_t)a * FEAT;
  const float* cn = proxies + (size_t)(a + 1 > NUM_AGES - 1 ? NUM_AGES - 1 : a + 1) * FEAT;
  const float* cp = proxies + (size_t)(a - 1 < 0 ? 0 : a - 1) * FEAT;
  const float* zr = z + (size_t)s * FEAT;

  float zf[2], dff[2], dbf[2];
  float s_ff = 0.f, s_bb = 0.f, s_zz = 0.f, s_zf = 0.f, s_zb = 0.f;
#pragma unroll
  for (int e = 0; e < 2; ++e) {
    int c = t + e * 256;
    float ccv = cc[c];
    dff[e] = cn[c] - ccv;
    dbf[e] = cp[c] - ccv;
    zf[e] = zr[c];
    s_ff += dff[e] * dff[e];
    s_bb += dbf[e] * dbf[e];
    s_zz += zf[e] * zf[e];
    s_zf += zf[e] * dff[e];
    s_zb += zf[e] * dbf[e];
  }
#pragma unroll
  for (int off = 32; off > 0; off >>= 1) {
    s_ff += __shfl_down(s_ff, off, 64);
    s_bb += __shfl_down(s_bb, off, 64);
    s_zz += __shfl_down(s_zz, off, 64);
    s_zf += __shfl_down(s_zf, off, 64);
    s_zb += __shfl_down(s_zb, off, 64);
  }
  __shared__ float red[4][5];
  int wv = t >> 6, lane = t & 63;
  if (lane == 0) {
    red[wv][0] = s_ff; red[wv][1] = s_bb; red[wv][2] = s_zz;
    red[wv][3] = s_zf; red[wv][4] = s_zb;
  }
  __syncthreads();
  float ff = red[0][0] + red[1][0] + red[2][0] + red[3][0];
  float bb = red[0][1] + red[1][1] + red[2][1] + red[3][1];
  float zz = red[0][2] + red[1][2] + red[2][2] + red[3][2];
  float zdf = red[0][3] + red[1][3] + red[2][3] + red[3][3];
  float zdb = red[0][4] + red[1][4] + red[2][4] + red[3][4];

  float rf = 1.0f / (sqrtf(ff) + EPSF);
  float rb = 1.0f / (sqrtf(bb) + EPSF);
  int key = (j >> 1) & 3;      // tile bases are multiples of 64 -> same key in-tile
#pragma unroll
  for (int e = 0; e < 2; ++e) {
    int c = t + e * 256;
    // swizzled column: permute 16B granule (c>>3)&3 within its 32-elem slab
    int c2 = (c & ~31) | (((((c >> 3) & 3) ^ key) << 3)) | (c & 7);
    float wval = dbf[e] * rb - dff[e] * rf;
    wb[(size_t)j * FEAT + c2] = (bf16_t)wval;
    zb[(size_t)j * FEAT + c2] = (bf16_t)zf[e];
  }
  if (t == 0) {
    sq[j] = zz;
    hd[j] = rb * zdb - rf * zdf;
    ages_s[j] = araw;
  }
}

// ---------------- kernel 2: fused pairwise tile (upper-tri band only) ----
// Age-sorted samples; tiles with i_min >= j_max+1 contribute 0 -> skipped.
// 124 total regs/wave (60 arch + 64 AGPR) -> 4 waves/SIMD via bounds(256,4).
__global__ __launch_bounds__(256, 4) void pair_kernel(
    const bf16_t* __restrict__ zb, const bf16_t* __restrict__ wb,
    const float* __restrict__ sq, const float* __restrict__ hd,
    const int* __restrict__ ages, float* __restrict__ out)
{
  // A: 128x32 bf16 = 8192 B | Z: 64x32 = 4096 B | W: 64x32 = 4096 B
  __shared__ __attribute__((aligned(16))) char lds[16384];
  __shared__ float s_sqi[BM];
  __shared__ int   s_agei[BM];
  __shared__ float s_sqj[BN];
  __shared__ float s_hdj[BN];
  __shared__ int   s_agej[BN];
  __shared__ float wsum[4];

  int t = threadIdx.x;
  int wv = t >> 6, lane = t & 63;

  // linear tile id -> (by, bx) with bx >= 2*by; row by has 64-2*by tiles
  int rem = blockIdx.x;
  int by = 0;
  while (rem >= 64 - 2 * by) { rem -= 64 - 2 * by; ++by; }
  int bx = 2 * by + rem;
  int i0 = by * BM, j0 = bx * BN;

  if (t < BM) {
    s_sqi[t] = sq[i0 + t];
    s_agei[t] = ages[i0 + t];
  } else if (t < BM + BN) {
    int u = t - BM;
    s_sqj[u] = sq[j0 + u];
    s_hdj[u] = hd[j0 + u];
    s_agej[u] = ages[j0 + u];
  }

  v4f accG[4][2], accH[4][2];
#pragma unroll
  for (int a = 0; a < 4; ++a)
#pragma unroll
    for (int b = 0; b < 2; ++b) {
      accG[a][b] = (v4f){0.f, 0.f, 0.f, 0.f};
      accH[a][b] = (v4f){0.f, 0.f, 0.f, 0.f};
    }

  int wm = wv >> 1, wn = wv & 1;        // wave grid 2x2: 64 rows x 32 cols each
  int lm = lane & 15, q = lane >> 4;
  // swizzled granule offset for fragment reads (key = (row>>1)&3 = (lm>>1)&3)
  int psw = (q ^ ((lm >> 1) & 3)) * 16;

  int grow = lane >> 2;                 // row within 16-row chunk
  int gcol = (lane & 3) * 8;            // bf16 element offset within 32-wide K slab

  const bf16_t* pA0 = zb + (size_t)(i0 + wv * 16 + grow) * FEAT + gcol;
  const bf16_t* pA1 = zb + (size_t)(i0 + 64 + wv * 16 + grow) * FEAT + gcol;
  const bf16_t* pZ  = zb + (size_t)(j0 + wv * 16 + grow) * FEAT + gcol;
  const bf16_t* pW  = wb + (size_t)(j0 + wv * 16 + grow) * FEAT + gcol;
  char* dA0 = lds + wv * 1024;
  char* dA1 = lds + 4096 + wv * 1024;
  char* dZ  = lds + 8192 + wv * 1024;
  char* dW  = lds + 12288 + wv * 1024;

  for (int k0 = 0; k0 < FEAT; k0 += BK) {
    async16(pA0, dA0);
    async16(pA1, dA1);
    async16(pZ, dZ);
    async16(pW, dW);
    pA0 += BK; pA1 += BK; pZ += BK; pW += BK;
    __syncthreads();

    v8bf afr[4], bz[2], bw[2];
#pragma unroll
    for (int mi = 0; mi < 4; ++mi) {
      int r = wm * 64 + mi * 16 + lm;
      afr[mi] = *(const v8bf*)(lds + r * 64 + psw);
    }
#pragma unroll
    for (int ni = 0; ni < 2; ++ni) {
      int r = wn * 32 + ni * 16 + lm;
      bz[ni] = *(const v8bf*)(lds + 8192 + r * 64 + psw);
      bw[ni] = *(const v8bf*)(lds + 12288 + r * 64 + psw);
    }
#pragma unroll
    for (int mi = 0; mi < 4; ++mi)
#pragma unroll
      for (int ni = 0; ni < 2; ++ni) {
        accG[mi][ni] = __builtin_amdgcn_mfma_f32_16x16x32_bf16(afr[mi], bz[ni], accG[mi][ni], 0, 0, 0);
        accH[mi][ni] = __builtin_amdgcn_mfma_f32_16x16x32_bf16(afr[mi], bw[ni], accH[mi][ni], 0, 0, 0);
      }
    __syncthreads();
  }

  // epilogue: C/D layout col = lane&15 (-> j), row = q*4 + reg (-> i)
  float tsum = 0.f;
#pragma unroll
  for (int ni = 0; ni < 2; ++ni) {
    int jl = wn * 32 + ni * 16 + lm;
    float sqj = s_sqj[jl];
    float hdj = s_hdj[jl];
    int aj = s_agej[jl];
#pragma unroll
    for (int mi = 0; mi < 4; ++mi) {
#pragma unroll
      for (int r = 0; r < 4; ++r) {
        int il = wm * 64 + mi * 16 + q * 4 + r;
        float g = accG[mi][ni][r];
        float h = accH[mi][ni][r];
        float d2 = fmaxf(s_sqi[il] + sqj - 2.0f * g, 1e-12f);
        float rs = __builtin_amdgcn_rsqf(d2);
        float arg = (h - hdj) * INV_T * rs;
        float sp = fmaxf(arg, 0.0f) + __logf(1.0f + __expf(-fabsf(arg)));
        tsum += (s_agei[il] < aj) ? sp : 0.0f;
      }
    }
  }

#pragma unroll
  for (int off = 32; off > 0; off >>= 1) tsum += __shfl_down(tsum, off, 64);
  if (lane == 0) wsum[wv] = tsum;
  __syncthreads();
  if (t == 0)
    atomicAdd(out, (wsum[0] + wsum[1] + wsum[2] + wsum[3]) * INV_NORM);
}

extern "C" void kernel_launch(void* const* d_in, const int* in_sizes, int n_in,
                              void* d_out, int out_size, void* d_ws, size_t ws_size,
                              hipStream_t stream) {
  const float* z = (const float*)d_in[0];
  const int* ages = (const int*)d_in[1];
  const float* proxies = (const float*)d_in[2];
  float* out = (float*)d_out;

  char* ws = (char*)d_ws;
  bf16_t* zb = (bf16_t*)ws;                                   // 4 MB
  bf16_t* wb = (bf16_t*)(ws + (size_t)4 * 1024 * 1024);       // 4 MB
  size_t o = (size_t)8 * 1024 * 1024;
  float* sq      = (float*)(ws + o);            // 16 KB
  float* hd      = (float*)(ws + o + 16384);    // 16 KB
  int*   perm    = (int*)  (ws + o + 32768);    // 16 KB
  int*   ages_s  = (int*)  (ws + o + 49152);    // 16 KB

  sort_kernel<<<1, 1024, 0, stream>>>(ages, perm, out);
  prep_kernel<<<BATCH, 256, 0, stream>>>(z, ages, proxies, perm, zb, wb, sq, hd, ages_s);
  pair_kernel<<<NTILES, 256, 0, stream>>>(zb, wb, sq, hd, ages_s, out);
}

// Round 7
// 106.255 us; speedup vs baseline: 1.0578x; 1.0461x over previous
//
#include <hip/hip_runtime.h>
#include <hip/hip_bf16.h>

#define NUM_AGES 100
#define FEAT 512
#define BATCH 4096
#define EPSF 1e-6f
#define INV_T 10.0f
#define INV_NORM (1.0f / ((float)BATCH * (float)(BATCH - 1)))

#define BM 128
#define BN 64
#define BK 32
// kept tiles: bx >= 2*by, by in [0,32), bx in [0,64) -> sum(64-2*by) = 1056
#define NTILES 1056

typedef __bf16 bf16_t;
typedef __bf16 v8bf __attribute__((ext_vector_type(8)));
typedef float v4f __attribute__((ext_vector_type(4)));

// async global->LDS, 16B per lane; LDS dest is wave-uniform base + lane*16
__device__ __forceinline__ void async16(const void* g, void* l) {
  __builtin_amdgcn_global_load_lds(
      (const __attribute__((address_space(1))) void*)g,
      (__attribute__((address_space(3))) void*)l, 16, 0, 0);
}

// ---------------- kernel 1: per-sample prep (inline rank + pre-swizzle) ---
// Block j computes rank(j) = #{k: a_k < a_j or (a_k==a_j and k<j)} (stable,
// bijective) and writes its sample's data to sorted position `rank` -- this
// replaces the serialized single-block counting-sort launch (R6 post-mortem).
// zb/wb columns are stored XOR-swizzled: within each 64B (32-elem) K-slab,
// the 16B granule g of row r sits at position g ^ ((r>>1)&3), so pair_kernel's
// monotonic global_load_lds staging lands a conflict-free LDS layout
// (2-way, free per m136) with zero change to its global access pattern.
__global__ __launch_bounds__(256) void prep_kernel(
    const float* __restrict__ z, const int* __restrict__ ages,
    const float* __restrict__ proxies,
    bf16_t* __restrict__ zb, bf16_t* __restrict__ wb,
    float* __restrict__ sq, float* __restrict__ hd,
    int* __restrict__ ages_s, float* __restrict__ out)
{
  int j = blockIdx.x;          // original sample index
  int t = threadIdx.x;
  if (j == 0 && t == 0) out[0] = 0.0f;   // pair_kernel accumulates into out

  int araw = ages[j];
  int a = araw < 0 ? 0 : (araw > NUM_AGES - 1 ? NUM_AGES - 1 : araw);
  const float* cc = proxies + (size_t)a * FEAT;
  const float* cn = proxies + (size_t)(a + 1 > NUM_AGES - 1 ? NUM_AGES - 1 : a + 1) * FEAT;
  const float* cp = proxies + (size_t)(a - 1 < 0 ? 0 : a - 1) * FEAT;
  const float* zr = z + (size_t)j * FEAT;

  // ---- rank of sample j in stable age order ----
  int cnt = 0;
#pragma unroll
  for (int e = 0; e < BATCH / 256; ++e) {
    int k = t + e * 256;
    int ak = ages[k];
    cnt += (ak < araw || (ak == araw && k < j)) ? 1 : 0;
  }

  float zf[2], dff[2], dbf[2];
  float s_ff = 0.f, s_bb = 0.f, s_zz = 0.f, s_zf = 0.f, s_zb = 0.f;
#pragma unroll
  for (int e = 0; e < 2; ++e) {
    int c = t + e * 256;
    float ccv = cc[c];
    dff[e] = cn[c] - ccv;
    dbf[e] = cp[c] - ccv;
    zf[e] = zr[c];
    s_ff += dff[e] * dff[e];
    s_bb += dbf[e] * dbf[e];
    s_zz += zf[e] * zf[e];
    s_zf += zf[e] * dff[e];
    s_zb += zf[e] * dbf[e];
  }
  float fcnt = (float)cnt;
#pragma unroll
  for (int off = 32; off > 0; off >>= 1) {
    s_ff += __shfl_down(s_ff, off, 64);
    s_bb += __shfl_down(s_bb, off, 64);
    s_zz += __shfl_down(s_zz, off, 64);
    s_zf += __shfl_down(s_zf, off, 64);
    s_zb += __shfl_down(s_zb, off, 64);
    fcnt += __shfl_down(fcnt, off, 64);
  }
  __shared__ float red[4][6];
  int wv = t >> 6, lane = t & 63;
  if (lane == 0) {
    red[wv][0] = s_ff; red[wv][1] = s_bb; red[wv][2] = s_zz;
    red[wv][3] = s_zf; red[wv][4] = s_zb; red[wv][5] = fcnt;
  }
  __syncthreads();
  float ff = red[0][0] + red[1][0] + red[2][0] + red[3][0];
  float bb = red[0][1] + red[1][1] + red[2][1] + red[3][1];
  float zz = red[0][2] + red[1][2] + red[2][2] + red[3][2];
  float zdf = red[0][3] + red[1][3] + red[2][3] + red[3][3];
  float zdb = red[0][4] + red[1][4] + red[2][4] + red[3][4];
  int rank = (int)(red[0][5] + red[1][5] + red[2][5] + red[3][5]);

  float rf = 1.0f / (sqrtf(ff) + EPSF);
  float rb = 1.0f / (sqrtf(bb) + EPSF);
  int key = (rank >> 1) & 3;   // tile bases are multiples of 64 -> same key in-tile
#pragma unroll
  for (int e = 0; e < 2; ++e) {
    int c = t + e * 256;
    // swizzled column: permute 16B granule (c>>3)&3 within its 32-elem slab
    int c2 = (c & ~31) | (((((c >> 3) & 3) ^ key) << 3)) | (c & 7);
    float wval = dbf[e] * rb - dff[e] * rf;
    wb[(size_t)rank * FEAT + c2] = (bf16_t)wval;
    zb[(size_t)rank * FEAT + c2] = (bf16_t)zf[e];
  }
  if (t == 0) {
    sq[rank] = zz;
    hd[rank] = rb * zdb - rf * zdf;
    ages_s[rank] = araw;
  }
}

// ---------------- kernel 2: fused pairwise tile (upper-tri band only) ----
// Age-sorted samples; tiles with i_min >= j_max+1 contribute 0 -> skipped.
// 124 total regs/wave (60 arch + 64 AGPR) -> 4 waves/SIMD via bounds(256,4).
__global__ __launch_bounds__(256, 4) void pair_kernel(
    const bf16_t* __restrict__ zb, const bf16_t* __restrict__ wb,
    const float* __restrict__ sq, const float* __restrict__ hd,
    const int* __restrict__ ages, float* __restrict__ out)
{
  // A: 128x32 bf16 = 8192 B | Z: 64x32 = 4096 B | W: 64x32 = 4096 B
  __shared__ __attribute__((aligned(16))) char lds[16384];
  __shared__ float s_sqi[BM];
  __shared__ int   s_agei[BM];
  __shared__ float s_sqj[BN];
  __shared__ float s_hdj[BN];
  __shared__ int   s_agej[BN];
  __shared__ float wsum[4];

  int t = threadIdx.x;
  int wv = t >> 6, lane = t & 63;

  // linear tile id -> (by, bx) with bx >= 2*by; row by has 64-2*by tiles
  int rem = blockIdx.x;
  int by = 0;
  while (rem >= 64 - 2 * by) { rem -= 64 - 2 * by; ++by; }
  int bx = 2 * by + rem;
  int i0 = by * BM, j0 = bx * BN;

  if (t < BM) {
    s_sqi[t] = sq[i0 + t];
    s_agei[t] = ages[i0 + t];
  } else if (t < BM + BN) {
    int u = t - BM;
    s_sqj[u] = sq[j0 + u];
    s_hdj[u] = hd[j0 + u];
    s_agej[u] = ages[j0 + u];
  }

  v4f accG[4][2], accH[4][2];
#pragma unroll
  for (int a = 0; a < 4; ++a)
#pragma unroll
    for (int b = 0; b < 2; ++b) {
      accG[a][b] = (v4f){0.f, 0.f, 0.f, 0.f};
      accH[a][b] = (v4f){0.f, 0.f, 0.f, 0.f};
    }

  int wm = wv >> 1, wn = wv & 1;        // wave grid 2x2: 64 rows x 32 cols each
  int lm = lane & 15, q = lane >> 4;
  // swizzled granule offset for fragment reads (key = (row>>1)&3 = (lm>>1)&3)
  int psw = (q ^ ((lm >> 1) & 3)) * 16;

  int grow = lane >> 2;                 // row within 16-row chunk
  int gcol = (lane & 3) * 8;            // bf16 element offset within 32-wide K slab

  const bf16_t* pA0 = zb + (size_t)(i0 + wv * 16 + grow) * FEAT + gcol;
  const bf16_t* pA1 = zb + (size_t)(i0 + 64 + wv * 16 + grow) * FEAT + gcol;
  const bf16_t* pZ  = zb + (size_t)(j0 + wv * 16 + grow) * FEAT + gcol;
  const bf16_t* pW  = wb + (size_t)(j0 + wv * 16 + grow) * FEAT + gcol;
  char* dA0 = lds + wv * 1024;
  char* dA1 = lds + 4096 + wv * 1024;
  char* dZ  = lds + 8192 + wv * 1024;
  char* dW  = lds + 12288 + wv * 1024;

  for (int k0 = 0; k0 < FEAT; k0 += BK) {
    async16(pA0, dA0);
    async16(pA1, dA1);
    async16(pZ, dZ);
    async16(pW, dW);
    pA0 += BK; pA1 += BK; pZ += BK; pW += BK;
    __syncthreads();

    v8bf afr[4], bz[2], bw[2];
#pragma unroll
    for (int mi = 0; mi < 4; ++mi) {
      int r = wm * 64 + mi * 16 + lm;
      afr[mi] = *(const v8bf*)(lds + r * 64 + psw);
    }
#pragma unroll
    for (int ni = 0; ni < 2; ++ni) {
      int r = wn * 32 + ni * 16 + lm;
      bz[ni] = *(const v8bf*)(lds + 8192 + r * 64 + psw);
      bw[ni] = *(const v8bf*)(lds + 12288 + r * 64 + psw);
    }
#pragma unroll
    for (int mi = 0; mi < 4; ++mi)
#pragma unroll
      for (int ni = 0; ni < 2; ++ni) {
        accG[mi][ni] = __builtin_amdgcn_mfma_f32_16x16x32_bf16(afr[mi], bz[ni], accG[mi][ni], 0, 0, 0);
        accH[mi][ni] = __builtin_amdgcn_mfma_f32_16x16x32_bf16(afr[mi], bw[ni], accH[mi][ni], 0, 0, 0);
      }
    __syncthreads();
  }

  // epilogue: C/D layout col = lane&15 (-> j), row = q*4 + reg (-> i)
  float tsum = 0.f;
#pragma unroll
  for (int ni = 0; ni < 2; ++ni) {
    int jl = wn * 32 + ni * 16 + lm;
    float sqj = s_sqj[jl];
    float hdj = s_hdj[jl];
    int aj = s_agej[jl];
#pragma unroll
    for (int mi = 0; mi < 4; ++mi) {
#pragma unroll
      for (int r = 0; r < 4; ++r) {
        int il = wm * 64 + mi * 16 + q * 4 + r;
        float g = accG[mi][ni][r];
        float h = accH[mi][ni][r];
        float d2 = fmaxf(s_sqi[il] + sqj - 2.0f * g, 1e-12f);
        float rs = __builtin_amdgcn_rsqf(d2);
        float arg = (h - hdj) * INV_T * rs;
        float sp = fmaxf(arg, 0.0f) + __logf(1.0f + __expf(-fabsf(arg)));
        tsum += (s_agei[il] < aj) ? sp : 0.0f;
      }
    }
  }

#pragma unroll
  for (int off = 32; off > 0; off >>= 1) tsum += __shfl_down(tsum, off, 64);
  if (lane == 0) wsum[wv] = tsum;
  __syncthreads();
  if (t == 0)
    atomicAdd(out, (wsum[0] + wsum[1] + wsum[2] + wsum[3]) * INV_NORM);
}

extern "C" void kernel_launch(void* const* d_in, const int* in_sizes, int n_in,
                              void* d_out, int out_size, void* d_ws, size_t ws_size,
                              hipStream_t stream) {
  const float* z = (const float*)d_in[0];
  const int* ages = (const int*)d_in[1];
  const float* proxies = (const float*)d_in[2];
  float* out = (float*)d_out;

  char* ws = (char*)d_ws;
  bf16_t* zb = (bf16_t*)ws;                                   // 4 MB
  bf16_t* wb = (bf16_t*)(ws + (size_t)4 * 1024 * 1024);       // 4 MB
  size_t o = (size_t)8 * 1024 * 1024;
  float* sq      = (float*)(ws + o);            // 16 KB
  float* hd      = (float*)(ws + o + 16384);    // 16 KB
  int*   ages_s  = (int*)  (ws + o + 32768);    // 16 KB

  prep_kernel<<<BATCH, 256, 0, stream>>>(z, ages, proxies, zb, wb, sq, hd, ages_s, out);
  pair_kernel<<<NTILES, 256, 0, stream>>>(zb, wb, sq, hd, ages_s, out);
}

// Round 8
// 104.908 us; speedup vs baseline: 1.0714x; 1.0128x over previous
//
#include <hip/hip_runtime.h>
#include <hip/hip_bf16.h>

#define NUM_AGES 100
#define FEAT 512
#define BATCH 4096
#define EPSF 1e-6f
#define INV_T 10.0f
#define INV_NORM (1.0f / ((float)BATCH * (float)(BATCH - 1)))

#define BM 128
#define BN 64
#define BK 64
// kept tiles: bx >= 2*by, by in [0,32), bx in [0,64) -> sum(64-2*by) = 1056
#define NTILES 1056

typedef __bf16 bf16_t;
typedef __bf16 v8bf __attribute__((ext_vector_type(8)));
typedef float v4f __attribute__((ext_vector_type(4)));

// async global->LDS, 16B per lane; LDS dest is wave-uniform base + lane*16
__device__ __forceinline__ void async16(const void* g, void* l) {
  __builtin_amdgcn_global_load_lds(
      (const __attribute__((address_space(1))) void*)g,
      (__attribute__((address_space(3))) void*)l, 16, 0, 0);
}

// ---------------- kernel 1: per-sample prep (inline rank + pre-swizzle) ---
// Block j computes rank(j) = #{k: a_k < a_j or (a_k==a_j and k<j)} (stable,
// bijective) and writes to sorted position `rank`. zb/wb are stored
// XOR-swizzled: within each 128B (64-elem) K-slab, logical 16B granule g of
// row r sits at physical position g ^ (r&7). pair_kernel's contiguous
// global_load_lds staging then lands a bank-balanced LDS layout (2 lanes per
// bank-quad = free) with zero change to its global access pattern.
__global__ __launch_bounds__(256) void prep_kernel(
    const float* __restrict__ z, const int* __restrict__ ages,
    const float* __restrict__ proxies,
    bf16_t* __restrict__ zb, bf16_t* __restrict__ wb,
    float* __restrict__ sq, float* __restrict__ hd,
    int* __restrict__ ages_s, float* __restrict__ out)
{
  int j = blockIdx.x;          // original sample index
  int t = threadIdx.x;
  if (j == 0 && t == 0) out[0] = 0.0f;   // pair_kernel accumulates into out

  int araw = ages[j];
  int a = araw < 0 ? 0 : (araw > NUM_AGES - 1 ? NUM_AGES - 1 : araw);
  const float* cc = proxies + (size_t)a * FEAT;
  const float* cn = proxies + (size_t)(a + 1 > NUM_AGES - 1 ? NUM_AGES - 1 : a + 1) * FEAT;
  const float* cp = proxies + (size_t)(a - 1 < 0 ? 0 : a - 1) * FEAT;
  const float* zr = z + (size_t)j * FEAT;

  // ---- rank of sample j in stable age order ----
  int cnt = 0;
#pragma unroll
  for (int e = 0; e < BATCH / 256; ++e) {
    int k = t + e * 256;
    int ak = ages[k];
    cnt += (ak < araw || (ak == araw && k < j)) ? 1 : 0;
  }

  // ---- vectorized per-sample math: thread t owns cols 2t, 2t+1 ----
  int c0 = 2 * t;
  float2 cc2 = *(const float2*)(cc + c0);
  float2 cn2 = *(const float2*)(cn + c0);
  float2 cp2 = *(const float2*)(cp + c0);
  float2 z2  = *(const float2*)(zr + c0);
  float df0 = cn2.x - cc2.x, df1 = cn2.y - cc2.y;
  float db0 = cp2.x - cc2.x, db1 = cp2.y - cc2.y;
  float s_ff = df0 * df0 + df1 * df1;
  float s_bb = db0 * db0 + db1 * db1;
  float s_zz = z2.x * z2.x + z2.y * z2.y;
  float s_zf = z2.x * df0 + z2.y * df1;
  float s_zb = z2.x * db0 + z2.y * db1;

  float fcnt = (float)cnt;
#pragma unroll
  for (int off = 32; off > 0; off >>= 1) {
    s_ff += __shfl_down(s_ff, off, 64);
    s_bb += __shfl_down(s_bb, off, 64);
    s_zz += __shfl_down(s_zz, off, 64);
    s_zf += __shfl_down(s_zf, off, 64);
    s_zb += __shfl_down(s_zb, off, 64);
    fcnt += __shfl_down(fcnt, off, 64);
  }
  __shared__ float red[4][6];
  int wv = t >> 6, lane = t & 63;
  if (lane == 0) {
    red[wv][0] = s_ff; red[wv][1] = s_bb; red[wv][2] = s_zz;
    red[wv][3] = s_zf; red[wv][4] = s_zb; red[wv][5] = fcnt;
  }
  __syncthreads();
  float ff = red[0][0] + red[1][0] + red[2][0] + red[3][0];
  float bb = red[0][1] + red[1][1] + red[2][1] + red[3][1];
  float zz = red[0][2] + red[1][2] + red[2][2] + red[3][2];
  float zdf = red[0][3] + red[1][3] + red[2][3] + red[3][3];
  float zdb = red[0][4] + red[1][4] + red[2][4] + red[3][4];
  int rank = (int)(red[0][5] + red[1][5] + red[2][5] + red[3][5]);

  float rf = 1.0f / (sqrtf(ff) + EPSF);
  float rb = 1.0f / (sqrtf(bb) + EPSF);
  int key = rank & 7;
  // swizzled column for the granule holding cols {2t, 2t+1}
  int c2s = (c0 & ~63) | (((((c0 >> 3) & 7) ^ key) << 3)) | (c0 & 7);
  float w0 = db0 * rb - df0 * rf;
  float w1 = db1 * rb - df1 * rf;
  union { bf16_t h[2]; unsigned u; } uz, uw;
  uz.h[0] = (bf16_t)z2.x; uz.h[1] = (bf16_t)z2.y;
  uw.h[0] = (bf16_t)w0;   uw.h[1] = (bf16_t)w1;
  *(unsigned*)((char*)zb + ((size_t)rank * FEAT + c2s) * 2) = uz.u;
  *(unsigned*)((char*)wb + ((size_t)rank * FEAT + c2s) * 2) = uw.u;
  if (t == 0) {
    sq[rank] = zz;
    hd[rank] = rb * zdb - rf * zdf;
    ages_s[rank] = araw;
  }
}

// ---------------- kernel 2: fused pairwise tile (upper-tri band only) ----
// Age-sorted samples; tiles with i_min >= j_max+1 contribute 0 -> skipped.
// BK=64: halves barrier count vs BK=32 (16 drains instead of 32); two
// 32-wide slabs processed sequentially per iter keep frag regs at 8 b128.
// 4 waves/SIMD via bounds(256,4); LDS 32K+2K x4 blocks/CU fits 160K.
__global__ __launch_bounds__(256, 4) void pair_kernel(
    const bf16_t* __restrict__ zb, const bf16_t* __restrict__ wb,
    const float* __restrict__ sq, const float* __restrict__ hd,
    const int* __restrict__ ages, float* __restrict__ out)
{
  // A: 128x64 bf16 = 16384 B | Z: 64x64 = 8192 B | W: 64x64 = 8192 B
  __shared__ __attribute__((aligned(16))) char lds[32768];
  __shared__ float s_sqi[BM];
  __shared__ int   s_agei[BM];
  __shared__ float s_sqj[BN];
  __shared__ float s_hdj[BN];
  __shared__ int   s_agej[BN];
  __shared__ float wsum[4];

  int t = threadIdx.x;
  int wv = t >> 6, lane = t & 63;

  // linear tile id -> (by, bx) with bx >= 2*by; row by has 64-2*by tiles
  int rem = blockIdx.x;
  int by = 0;
  while (rem >= 64 - 2 * by) { rem -= 64 - 2 * by; ++by; }
  int bx = 2 * by + rem;
  int i0 = by * BM, j0 = bx * BN;

  if (t < BM) {
    s_sqi[t] = sq[i0 + t];
    s_agei[t] = ages[i0 + t];
  } else if (t < BM + BN) {
    int u = t - BM;
    s_sqj[u] = sq[j0 + u];
    s_hdj[u] = hd[j0 + u];
    s_agej[u] = ages[j0 + u];
  }

  v4f accG[4][2], accH[4][2];
#pragma unroll
  for (int a = 0; a < 4; ++a)
#pragma unroll
    for (int b = 0; b < 2; ++b) {
      accG[a][b] = (v4f){0.f, 0.f, 0.f, 0.f};
      accH[a][b] = (v4f){0.f, 0.f, 0.f, 0.f};
    }

  int wm = wv >> 1, wn = wv & 1;        // wave grid 2x2: 64 rows x 32 cols each
  int lm = lane & 15, q = lane >> 4;
  // swizzled granule byte offsets for the two 32-elem slabs (key = lm&7)
  int psw0 = ((q     ) ^ (lm & 7)) * 16;
  int psw1 = ((q + 4 ) ^ (lm & 7)) * 16;

  // staging: per async16, lane l covers row (l>>3), physical granule (l&7)
  // of an 8-row x 128B chunk (contiguous copy preserves prep's swizzle).
  int loff = (lane >> 3) * FEAT + (lane & 7) * 8;   // bf16 elements
  const bf16_t* baseA = zb + (size_t)i0 * FEAT + loff;
  const bf16_t* baseZ = zb + (size_t)j0 * FEAT + loff;
  const bf16_t* baseW = wb + (size_t)j0 * FEAT + loff;

  for (int k0 = 0; k0 < FEAT; k0 += BK) {
    // A: 16 chunks of 8 rows; wave wv does chunks wv*4..wv*4+3
#pragma unroll
    for (int c = 0; c < 4; ++c) {
      int chunk = wv * 4 + c;
      async16(baseA + (size_t)chunk * 8 * FEAT + k0, lds + chunk * 1024);
    }
    // Z, W: 8 chunks each; wave wv does chunks wv*2, wv*2+1
#pragma unroll
    for (int c = 0; c < 2; ++c) {
      int chunk = wv * 2 + c;
      async16(baseZ + (size_t)chunk * 8 * FEAT + k0, lds + 16384 + chunk * 1024);
      async16(baseW + (size_t)chunk * 8 * FEAT + k0, lds + 24576 + chunk * 1024);
    }
    __syncthreads();

#pragma unroll
    for (int s = 0; s < 2; ++s) {
      int psw = s ? psw1 : psw0;
      v8bf afr[4], bz[2], bw[2];
#pragma unroll
      for (int mi = 0; mi < 4; ++mi) {
        int r = wm * 64 + mi * 16 + lm;
        afr[mi] = *(const v8bf*)(lds + r * 128 + psw);
      }
#pragma unroll
      for (int ni = 0; ni < 2; ++ni) {
        int r = wn * 32 + ni * 16 + lm;
        bz[ni] = *(const v8bf*)(lds + 16384 + r * 128 + psw);
        bw[ni] = *(const v8bf*)(lds + 24576 + r * 128 + psw);
      }
#pragma unroll
      for (int mi = 0; mi < 4; ++mi)
#pragma unroll
        for (int ni = 0; ni < 2; ++ni) {
          accG[mi][ni] = __builtin_amdgcn_mfma_f32_16x16x32_bf16(afr[mi], bz[ni], accG[mi][ni], 0, 0, 0);
          accH[mi][ni] = __builtin_amdgcn_mfma_f32_16x16x32_bf16(afr[mi], bw[ni], accH[mi][ni], 0, 0, 0);
        }
    }
    __syncthreads();
  }

  // epilogue: C/D layout col = lane&15 (-> j), row = q*4 + reg (-> i)
  float tsum = 0.f;
#pragma unroll
  for (int ni = 0; ni < 2; ++ni) {
    int jl = wn * 32 + ni * 16 + lm;
    float sqj = s_sqj[jl];
    float hdj = s_hdj[jl];
    int aj = s_agej[jl];
#pragma unroll
    for (int mi = 0; mi < 4; ++mi) {
#pragma unroll
      for (int r = 0; r < 4; ++r) {
        int il = wm * 64 + mi * 16 + q * 4 + r;
        float g = accG[mi][ni][r];
        float h = accH[mi][ni][r];
        float d2 = fmaxf(s_sqi[il] + sqj - 2.0f * g, 1e-12f);
        float rs = __builtin_amdgcn_rsqf(d2);
        float arg = (h - hdj) * INV_T * rs;
        float sp = fmaxf(arg, 0.0f) + __logf(1.0f + __expf(-fabsf(arg)));
        tsum += (s_agei[il] < aj) ? sp : 0.0f;
      }
    }
  }

#pragma unroll
  for (int off = 32; off > 0; off >>= 1) tsum += __shfl_down(tsum, off, 64);
  if (lane == 0) wsum[wv] = tsum;
  __syncthreads();
  if (t == 0)
    atomicAdd(out, (wsum[0] + wsum[1] + wsum[2] + wsum[3]) * INV_NORM);
}

extern "C" void kernel_launch(void* const* d_in, const int* in_sizes, int n_in,
                              void* d_out, int out_size, void* d_ws, size_t ws_size,
                              hipStream_t stream) {
  const float* z = (const float*)d_in[0];
  const int* ages = (const int*)d_in[1];
  const float* proxies = (const float*)d_in[2];
  float* out = (float*)d_out;

  char* ws = (char*)d_ws;
  bf16_t* zb = (bf16_t*)ws;                                   // 4 MB
  bf16_t* wb = (bf16_t*)(ws + (size_t)4 * 1024 * 1024);       // 4 MB
  size_t o = (size_t)8 * 1024 * 1024;
  float* sq      = (float*)(ws + o);            // 16 KB
  float* hd      = (float*)(ws + o + 16384);    // 16 KB
  int*   ages_s  = (int*)  (ws + o + 32768);    // 16 KB

  prep_kernel<<<BATCH, 256, 0, stream>>>(z, ages, proxies, zb, wb, sq, hd, ages_s, out);
  pair_kernel<<<NTILES, 256, 0, stream>>>(zb, wb, sq, hd, ages_s, out);
}